// Round 14
// baseline (311.145 us; speedup 1.0000x reference)
//
#include <hip/hip_runtime.h>
#include <hip/hip_bf16.h>
#include <math.h>

typedef __hip_bfloat16 hbf;
typedef short bf16x8 __attribute__((ext_vector_type(8)));
typedef short bf16x4 __attribute__((ext_vector_type(4)));
typedef float f32x4 __attribute__((ext_vector_type(4)));

// ---------------- problem constants ----------------
constexpr int NL  = 4096;
constexpr int HH  = 256;
constexpr int NE  = 8192;
constexpr int DIc = 512;
constexpr int DSc = 8;
constexpr int CLc = 16;    // scan chunk length (256 chunks)
constexpr int NOUT = 12416;

// ---------------- workspace layout (float offsets) ----------------
constexpr size_t O_MBUF  = 0;         // 1048576  agg bf16; scan P; attn op0/op1(bf16)
constexpr size_t O_QK    = 1048576;   // 1048576  scan Hl (temp)
constexpr size_t O_H2    = 2097152;   // 1048576  h2 fp32 (live to fus resid)
constexpr size_t O_CATB  = 3145728;   // 1572864  catb bf16 [NL][768]
constexpr size_t O_XZB   = 4718592;   // 2097152  xzb bf16 [NL][1024]
constexpr size_t O_XC    = 6815744;   // 2097152  csr (early phase) THEN fused fp32 (epilogue)
constexpr size_t O_DELTA = 8912896;   // 2097152  delta; attn op2/op3(bf16) after scan3
constexpr size_t O_PROJ  = 11010048;  // 131072   proj fp32
constexpr size_t O_HST   = 11141120;  // 1048576  Hst; lsum after scan3
constexpr size_t O_Y     = 12189696;  // 1048576  yb bf16; aob bf16
constexpr size_t O_POOL  = 13238272;  // 2048
constexpr size_t O_DINV  = 13240320;  // 4096 (unused, kept for layout stability)
constexpr size_t O_B768  = 13244416;  // 768
constexpr size_t O_INT   = 13245184;  // 81928 ints (cnt 4096 here)
constexpr size_t O_WT    = 13327112;  // 512000
constexpr size_t O_XB    = 13839112;  // 65536
constexpr size_t O_H0B   = 13904648;  // 524288  h0b, then h1b (reuse)
constexpr size_t O_H2B   = 14428936;  // 524288
constexpr size_t O_XCB   = 14953224;  // 1048576
constexpr size_t O_DTAB  = 16001800;  // 65536
constexpr size_t O_QKB   = 16067584;  // 1048576  qkB bf16 [NL][512]
constexpr size_t O_VTB   = 17116160;  // 524288   vtB bf16 [256][NL]
constexpr size_t O_HWT   = 17902592;  // transposed head weights [1552][256] bf16 (397312)
constexpr size_t O_PART  = 18350080;  // 1048576  ln partial pools [512][2048] (atomic-free)

// ---------------- transpose-cast tables ----------------
constexpr int NW = 12;
__device__ __constant__ int wc_cum[NW+1] = {
    0, 8192, 73728, 139264, 155648, 172032, 303104, 565248,
    630784, 696320, 761856, 827392, 1024000 };
constexpr int NT = 15;
__device__ __constant__ int tc_cum[NT+1] = {
    0, 8, 72, 136, 152, 168, 296, 552, 616, 680, 744, 808, 1000, 1128, 1256, 1384 };
__device__ __constant__ int tc_kt[NT] = {1,8,8,16,1,16,8,8,8,8,8,24,8,8,8};
__device__ __constant__ int tc_K [NT] = {32,256,256,512,16,512,256,256,256,256,256,768,256,256,256};
__device__ __constant__ int tc_N [NT] = {256,256,256,32,512,256,1024,256,256,256,256,256,512,512,512};
__device__ __constant__ int tc_Kp[NT] = {32,256,256,512,32,512,256,256,256,256,256,768,256,256,256};
__device__ __constant__ int hw_off[3] = {2048, 133120, 264192};  // j=8,520,1032 (x256) in hwt

struct WSrc { const float* p[NT]; };
struct HSrc4 { const float* p[4]; };  // cw, hw, tw, sw (small head cols)
struct OPtrs { hbf* p[4]; };

// prep: tiled weight transposes (blocks < TTILES) + misc tail
constexpr int TTILES = 1384;
constexpr int M_X = 131072;
constexpr int M_B = M_X + 768;        // 131840
constexpr int M_P = M_B + 1048576;    // 1180416 (part zero, 4 MB)
constexpr int M_C = M_P + 4096;       // 1184512
constexpr int M_H = M_C + 4096;       // 1188608
constexpr int PREP_BLKS = TTILES + M_H/256;   // 1384 + 4643 = 6027

__global__ __launch_bounds__(256) void prep_k(WSrc ws, hbf* __restrict__ wt,
        hbf* __restrict__ hwt,
        const float* __restrict__ x, hbf* __restrict__ xb,
        const float* __restrict__ bq, const float* __restrict__ bk,
        const float* __restrict__ bv,
        float* __restrict__ b768, float* __restrict__ part, int* __restrict__ cnt,
        HSrc4 hs) {
    __shared__ float T[32][33];
    int bid = blockIdx.x, t = threadIdx.x;
    if (bid < TTILES) {
        int lo = 0, hi = NT-1;
        while (lo < hi) { int mid = (lo+hi+1)>>1; if (bid >= tc_cum[mid]) lo = mid; else hi = mid-1; }
        int lt = bid - tc_cum[lo];
        int ktl = tc_kt[lo];
        int tn = lt / ktl, tk = lt - tn*ktl;
        int K = tc_K[lo], N = tc_N[lo], Kp = tc_Kp[lo];
        const float* src = ws.p[lo];
        int r = t >> 3, c4 = (t & 7) << 2;
        int k0 = tk*32, n0 = tn*32;
        float4 v = make_float4(0.f, 0.f, 0.f, 0.f);
        if (k0 + r < K)
            v = *(const float4*)&src[(size_t)(k0+r)*N + n0 + c4];
        T[r][c4]   = v.x; T[r][c4+1] = v.y; T[r][c4+2] = v.z; T[r][c4+3] = v.w;
        __syncthreads();
        hbf o[4] __attribute__((aligned(8)));
        #pragma unroll
        for (int j = 0; j < 4; j++) o[j] = __float2bfloat16(T[c4+j][r]);
        hbf* dstp = (lo < NW) ? (wt + wc_cum[lo]) : (hwt + hw_off[lo - NW]);
        *(uint2*)&dstp[(size_t)(n0+r)*Kp + k0 + c4] = *(uint2*)o;
    } else {
        int idx = (bid - TTILES)*256 + t;
        if (idx < M_X) {
            xb[idx] = __float2bfloat16(x[idx]);
        } else if (idx < M_B) {
            int i = idx - M_X;
            b768[i] = (i < 256) ? bq[i] : (i < 512 ? bk[i-256] : bv[i-512]);
        } else if (idx < M_P) {
            part[idx - M_B] = 0.0f;
        } else if (idx < M_C) {
            cnt[idx - M_P] = 0;
        } else {
            int i = idx - M_C;
            int jj = i >> 8, k = i & 255;
            int j = (jj < 8) ? jj : (1536 + jj);
            const float* sp; int col, nc;
            if (j < 1)       { sp = hs.p[0]; col = j;        nc = 1; }
            else if (j < 5)  { sp = hs.p[1]; col = j - 1;    nc = 4; }
            else if (j < 8)  { sp = hs.p[2]; col = j - 5;    nc = 3; }
            else             { sp = hs.p[3]; col = j - 1544; nc = 8; }
            hwt[(size_t)j*256 + k] = __float2bfloat16(sp[(size_t)k*nc + col]);
        }
    }
}

// ---------------- graph prep: single-kernel bucket CSR (cap 64/node, 12-sigma safe + guarded) ----------------
__global__ void bucket_k(const int* __restrict__ ei, int* __restrict__ cnt,
                         int* __restrict__ csr) {
    int i = blockIdx.x*256 + threadIdx.x;
    int b = i >> 13, e = i & 8191;
    int src = ei[b*2*NE + e]      + (b << 9);
    int dst = ei[b*2*NE + NE + e] + (b << 9);
    int slot = atomicAdd(&cnt[dst], 1);
    if (slot < 64) csr[(dst << 6) + slot] = src;
}

// gather: 8 nodes/block, 32 lanes x bf16x8 per node (16B/lane loads, 8 independent
// latency chains per block). Accumulation order bit-identical to 2-acc even/odd scheme.
__global__ __launch_bounds__(256) void gather_k(const hbf* __restrict__ m,
                        const int* __restrict__ csr, const int* __restrict__ cnt,
                        hbf* __restrict__ outb) {
    __shared__ int   sidx[8][64];
    __shared__ float sdv[8][64];
    int t = threadIdx.x;
    int ni = t >> 5, l32 = t & 31;
    int n = blockIdx.x*8 + ni;
    int cn = min(cnt[n], 64);
    for (int e = l32; e < cn; e += 32) {
        int s = csr[(n << 6) + e];
        sidx[ni][e] = s;
        sdv[ni][e]  = rsqrtf(1.0f + (float)min(cnt[s], 64));
    }
    __syncthreads();
    float dn = rsqrtf(1.0f + (float)cn);
    int c8 = l32 << 3;
    float a0[8], a1[8];
    {
        bf16x8 v = *(const bf16x8*)&m[(size_t)n*HH + c8];
        #pragma unroll
        for (int j = 0; j < 8; j++) {
            short tv = v[j]; hbf hv; *(short*)&hv = tv;
            a0[j] = __bfloat162float(hv) * dn;
            a1[j] = 0.0f;
        }
    }
    int e = 0;
    for (; e + 1 < cn; e += 2) {
        bf16x8 v0 = *(const bf16x8*)&m[(size_t)sidx[ni][e]  *HH + c8];
        bf16x8 v1 = *(const bf16x8*)&m[(size_t)sidx[ni][e+1]*HH + c8];
        float d0 = sdv[ni][e], d1 = sdv[ni][e+1];
        #pragma unroll
        for (int j = 0; j < 8; j++) {
            short t0 = v0[j]; hbf h0; *(short*)&h0 = t0;
            short t1 = v1[j]; hbf h1; *(short*)&h1 = t1;
            a0[j] += __bfloat162float(h0) * d0;
            a1[j] += __bfloat162float(h1) * d1;
        }
    }
    if (e < cn) {
        bf16x8 v0 = *(const bf16x8*)&m[(size_t)sidx[ni][e]*HH + c8];
        float d0 = sdv[ni][e];
        #pragma unroll
        for (int j = 0; j < 8; j++) {
            short t0 = v0[j]; hbf h0; *(short*)&h0 = t0;
            a0[j] += __bfloat162float(h0) * d0;
        }
    }
    hbf out[8] __attribute__((aligned(16)));
    #pragma unroll
    for (int j = 0; j < 8; j++) out[j] = __float2bfloat16((a0[j] + a1[j]) * dn);
    *(uint4*)&outb[(size_t)n*HH + c8] = *(uint4*)out;
}

// ---------------- bf16 MFMA GEMM: 256 threads / 4 waves, 32x32 tile, BK=64 ----------------
// OUTM: 0 fp32, 1 bf16, 4 proj+dtab, 5 fused in_proj+QKV, 6 gcn2 triple-out (fp32+bf16+catb)
// ACT: 0 none, 1 relu, 2 softplus
template<int ACT, int OUTM>
__global__ __launch_bounds__(256) void mg_k(const unsigned short* __restrict__ A,
        const unsigned short* __restrict__ Bt, const float* __restrict__ bias,
        void* __restrict__ Cp, int ldc, void* __restrict__ Cp2, void* __restrict__ Cp3,
        const float* __restrict__ resid, int ldr, int M, int K, int N)
{
    __shared__ __align__(16) unsigned short Asm[2][32][40];
    __shared__ __align__(16) unsigned short Bsm[2][32][40];
    int t = threadIdx.x;
    int lane = t & 63, w = t >> 6;              // 4 waves
    int wr = (w & 1) * 16, wc = (w >> 1) * 16;  // wave quadrant
    int row0 = blockIdx.x * 32, col0 = blockIdx.y * 32;
    int sr = t >> 3, sk8 = (t & 7) * 8;         // staging: 32 rows x 64k, 1 uint4/thread
    f32x4 acc = {};
    int fr = lane & 15, fq8 = (lane >> 4) * 8;

    uint4 zz = make_uint4(0u,0u,0u,0u);
    uint4 ra = zz, rb = zz;
    if (sk8 < K) {
        ra = *(const uint4*)&A[(size_t)(row0+sr)*K + sk8];
        rb = *(const uint4*)&Bt[(size_t)(col0+sr)*K + sk8];
    }

    for (int k0 = 0; k0 < K; k0 += 64) {
        __syncthreads();
        *(uint4*)&Asm[sk8>>5][sr][sk8 & 31] = ra;
        *(uint4*)&Bsm[sk8>>5][sr][sk8 & 31] = rb;
        __syncthreads();
        int kn = k0 + 64;
        if (kn < K) {
            ra = rb = zz;
            if (kn + sk8 < K) {
                ra = *(const uint4*)&A[(size_t)(row0+sr)*K + kn + sk8];
                rb = *(const uint4*)&Bt[(size_t)(col0+sr)*K + kn + sk8];
            }
        }
        #pragma unroll
        for (int ks = 0; ks < 2; ks++) {
            bf16x8 a = *(bf16x8*)&Asm[ks][wr + fr][fq8];
            bf16x8 b = *(bf16x8*)&Bsm[ks][wc + fr][fq8];
            acc = __builtin_amdgcn_mfma_f32_16x16x32_bf16(a, b, acc, 0, 0, 0);
        }
    }

    int fc = lane & 15, frq = (lane >> 4) * 4;
    if constexpr (OUTM == 4) {
        int col = wc + fc;                      // col0 == 0, tile exactly 32 wide
        #pragma unroll
        for (int i = 0; i < 4; i++) {
            int row = row0 + wr + frq + i;
            float v = acc[i];
            ((float*)Cp)[(size_t)row*32 + col] = v;
            ((hbf*)Cp2)[(size_t)row*32 + col] = __float2bfloat16((col < 16) ? v : 0.0f);
        }
    } else if constexpr (OUTM == 5) {
        if (col0 < 1024) {
            int col = col0 + wc + fc;
            #pragma unroll
            for (int i = 0; i < 4; i++) {
                int row = row0 + wr + frq + i;
                ((hbf*)Cp)[(size_t)row*1024 + col] = __float2bfloat16(acc[i]);
            }
        } else if (col0 < 1536) {
            int gcol = col0 + wc + fc;
            int col = gcol - 1024;
            float bvv = bias[col];
            float sc = (col < 256) ? 0.125f : 1.0f;
            #pragma unroll
            for (int i = 0; i < 4; i++) {
                int row = row0 + wr + frq + i;
                ((hbf*)Cp2)[(size_t)row*512 + col] = __float2bfloat16((acc[i] + bvv) * sc);
            }
        } else {
            __shared__ __align__(16) unsigned short Ts[32][48];
            int gcol = col0 + wc + fc;
            float bvv = bias[gcol - 1024];
            #pragma unroll
            for (int i = 0; i < 4; i++)
                *(hbf*)&Ts[wc + fc][wr + frq + i] = __float2bfloat16(acc[i] + bvv);
            __syncthreads();
            if (t < 128) {
                int c = t >> 2, rs = (t & 3) * 8;
                *(uint4*)((hbf*)Cp3 + (size_t)(col0 - 1536 + c)*NL + row0 + rs) = *(uint4*)&Ts[c][rs];
            }
        }
    } else if constexpr (OUTM == 6) {
        int col = col0 + wc + fc;
        float bvv = bias[col];
        #pragma unroll
        for (int i = 0; i < 4; i++) {
            int row = row0 + wr + frq + i;
            float v = fmaxf(acc[i] + bvv, 0.0f);
            ((float*)Cp)[(size_t)row*HH + col] = v;
            hbf hv = __float2bfloat16(v);
            ((hbf*)Cp2)[(size_t)row*HH + col] = hv;
            ((hbf*)Cp3)[(size_t)row*768 + col] = hv;
        }
    } else {
        int col = col0 + wc + fc;
        if (col < N) {
            float bvv = bias ? bias[col] : 0.0f;
            #pragma unroll
            for (int i = 0; i < 4; i++) {
                int row = row0 + wr + frq + i;
                float v = acc[i] + bvv;
                if (ACT == 1) v = fmaxf(v, 0.0f);
                if (ACT == 2) v = (v > 20.0f) ? v : log1pf(expf(v));
                if (resid) v += resid[(size_t)row*ldr + col];
                if (OUTM == 0) ((float*)Cp)[(size_t)row*ldc + col] = v;
                else           ((hbf*)Cp)[(size_t)row*ldc + col] = __float2bfloat16(v);
            }
        }
    }
}

// ---------------- mamba: conv + silu, vectorized bf16x8 (8 outputs/thread) ----------------
__global__ __launch_bounds__(256) void conv_k(const hbf* __restrict__ xzb,
                       const float* __restrict__ cW,
                       const float* __restrict__ cb, hbf* __restrict__ xcb) {
    int i = blockIdx.x*256 + threadIdx.x;      // 262144 threads: l = i>>6, d8 = (i&63)*8
    int l = i >> 6, d8 = (i & 63) << 3;
    float acc[8];
    {
        float4 c0 = *(const float4*)&cb[d8];
        float4 c1 = *(const float4*)&cb[d8+4];
        acc[0]=c0.x; acc[1]=c0.y; acc[2]=c0.z; acc[3]=c0.w;
        acc[4]=c1.x; acc[5]=c1.y; acc[6]=c1.z; acc[7]=c1.w;
    }
    float4 cw4[8];
    #pragma unroll
    for (int j = 0; j < 8; j++) cw4[j] = *(const float4*)&cW[(d8+j)*4];
    #pragma unroll
    for (int k = 0; k < 4; k++) {
        int ls = l - 3 + k;
        if (ls < 0) continue;
        bf16x8 v = *(const bf16x8*)&xzb[(size_t)ls*1024 + d8];
        #pragma unroll
        for (int j = 0; j < 8; j++) {
            short tv = v[j]; hbf hv; *(short*)&hv = tv;
            float wk = (k == 0) ? cw4[j].x : (k == 1) ? cw4[j].y : (k == 2) ? cw4[j].z : cw4[j].w;
            acc[j] += __bfloat162float(hv) * wk;
        }
    }
    hbf out[8];
    #pragma unroll
    for (int j = 0; j < 8; j++) {
        float r = acc[j] / (1.0f + __expf(-acc[j]));
        out[j] = __float2bfloat16(r);
    }
    *(uint4*)&xcb[(size_t)l*512 + d8] = *(uint4*)out;
}

// ---------------- mamba chunked scan (256 chunks x 16 steps) ----------------
__global__ __launch_bounds__(256) void scan1_k(const float* __restrict__ delta,
                        const hbf* __restrict__ xc, const float* __restrict__ proj,
                        const float* __restrict__ Alog,
                        float* __restrict__ P, float* __restrict__ Hl)
{
    int c = blockIdx.x >> 1;
    int d = ((blockIdx.x & 1) << 8) + threadIdx.x;
    float Ac[DSc], pr[DSc], h[DSc];
    #pragma unroll
    for (int s2 = 0; s2 < DSc; s2++) { Ac[s2] = -__expf(Alog[d*DSc+s2]); pr[s2]=1.0f; h[s2]=0.0f; }
    int l0 = c * CLc;
    for (int l = l0; l < l0 + CLc; l++) {
        float dl = delta[(size_t)l*DIc + d];
        float dx = dl * __bfloat162float(xc[(size_t)l*DIc + d]);
        const float* pb = proj + l*32 + 16;
        #pragma unroll
        for (int s2 = 0; s2 < DSc; s2++) {
            float a = __expf(dl * Ac[s2]);
            h[s2] = a*h[s2] + dx*pb[s2];
            pr[s2] *= a;
        }
    }
    #pragma unroll
    for (int s2 = 0; s2 < DSc; s2++) {
        P [(size_t)(c*DSc+s2)*DIc + d] = pr[s2];
        Hl[(size_t)(c*DSc+s2)*DIc + d] = h[s2];
    }
}

// coalesced middle scan: block = 16 consecutive series, LDS tile [256 chunks][16 series]
__global__ __launch_bounds__(256) void scan2t_k(const float* __restrict__ P,
                        const float* __restrict__ Hl, float* __restrict__ Hst) {
    __shared__ float Ps[256][17], Hs[256][17];
    int t = threadIdx.x, sg = blockIdx.x;
    int si = t & 15, cb = t >> 4;
    #pragma unroll
    for (int it = 0; it < 16; it++) {
        int c = it*16 + cb;
        size_t off = (size_t)c*4096 + sg*16 + si;
        Ps[c][si] = P[off];
        Hs[c][si] = Hl[off];
    }
    __syncthreads();
    int si2 = t >> 4, g = t & 15;
    int lane = t & 63;
    float Pg = 1.0f, Hg = 0.0f;
    #pragma unroll
    for (int j = 0; j < 16; j++) {
        int c = g*16 + j;
        float pc = Ps[c][si2], hc = Hs[c][si2];
        Hg = hc + pc*Hg;
        Pg = pc*Pg;
    }
    #pragma unroll
    for (int off = 1; off < 16; off <<= 1) {
        float Pp = __shfl(Pg, lane - off);
        float Hp = __shfl(Hg, lane - off);
        if (g >= off) { Hg = Hg + Pg*Hp; Pg = Pg*Pp; }
    }
    float carry = __shfl(Hg, lane - 1);
    if (g == 0) carry = 0.0f;
    float h = carry;
    #pragma unroll
    for (int j = 0; j < 16; j++) {
        int c = g*16 + j;
        float pc = Ps[c][si2], hc = Hs[c][si2];
        Hs[c][si2] = h;
        h = hc + pc*h;
    }
    __syncthreads();
    #pragma unroll
    for (int it = 0; it < 16; it++) {
        int c = it*16 + cb;
        Hst[(size_t)c*4096 + sg*16 + si] = Hs[c][si];
    }
}

__global__ __launch_bounds__(256) void scan3_k(const float* __restrict__ delta,
                        const hbf* __restrict__ xc, const float* __restrict__ proj,
                        const float* __restrict__ Alog, const float* __restrict__ Hst,
                        const float* __restrict__ Dp, const hbf* __restrict__ xzb,
                        hbf* __restrict__ Y)
{
    int c = blockIdx.x >> 1;
    int d = ((blockIdx.x & 1) << 8) + threadIdx.x;
    float Ac[DSc], h[DSc];
    #pragma unroll
    for (int s2 = 0; s2 < DSc; s2++) {
        Ac[s2] = -__expf(Alog[d*DSc+s2]);
        h[s2]  = Hst[(size_t)(c*DSc+s2)*DIc + d];
    }
    float dpv = Dp[d];
    int l0 = c * CLc;
    for (int l = l0; l < l0 + CLc; l++) {
        float dl = delta[(size_t)l*DIc + d];
        float xv = __bfloat162float(xc[(size_t)l*DIc + d]);
        float dx = dl * xv;
        const float* pb = proj + l*32 + 16;
        float y = 0.0f;
        #pragma unroll
        for (int s2 = 0; s2 < DSc; s2++) {
            float a = __expf(dl * Ac[s2]);
            h[s2] = a*h[s2] + dx*pb[s2];
            y += h[s2] * pb[8+s2];
        }
        float z = __bfloat162float(xzb[(size_t)l*1024 + 512 + d]);
        float sz = z / (1.0f + __expf(-z));
        Y[(size_t)l*DIc + d] = __float2bfloat16((y + dpv*xv) * sz);
    }
}

// ---------------- split-K(4) MFMA flash attention, TQ=128, constant-shift softmax ----------------
// Swapped-operand QK (S^T = mfma(K,Q)): lane's S fragment IS the PV B-operand fragment.
// lsum row-sum is lane-local f32 accumulation + 2 shfl_xor folds.
__global__ __launch_bounds__(512, 8) void attn_part_k(const unsigned short* __restrict__ QK,
                       const unsigned short* __restrict__ Vt,
                       OPtrs op, float* __restrict__ lsum)
{
    __shared__ __align__(16) unsigned short QPs[128][72];
    __shared__ __align__(16) unsigned short Ks[64][72];
    __shared__ __align__(16) unsigned short Vs[64][72];
    int t = threadIdx.x, lane = t & 63, w = t >> 6;
    int h = blockIdx.y, q0 = blockIdx.x * 128, skc = blockIdx.z;
    int fm = lane & 15, fq = lane >> 4;

    {
        int qr = t >> 2, qc = (t & 3) * 16;
        const unsigned short* src = &QK[(size_t)(q0+qr)*512 + h*64 + qc];
        *(uint4*)&QPs[qr][qc]     = *(const uint4*)&src[0];
        *(uint4*)&QPs[qr][qc + 8] = *(const uint4*)&src[8];
    }
    __syncthreads();
    bf16x8 qa[2];   // B-operand of S^T: col=lane&15 -> q, k=(lane>>4)*8+j -> head-dim d
    #pragma unroll
    for (int ks = 0; ks < 2; ks++)
        qa[ks] = *(bf16x8*)&QPs[w*16 + fm][ks*32 + fq*8];

    f32x4 o[4] = {};   // o^T: col=lane&15=q, row=(lane>>4)*4+i = d within subtile ntd
    float psum = 0.0f;
    int sr = t >> 3, sk = (t & 7) * 8;
    const unsigned short* Kb = QK + 256;
    int kt = skc * 1024;
    uint4 ka = *(const uint4*)&Kb[(size_t)(kt+sr)*512 + h*64 + sk];
    uint4 va = *(const uint4*)&Vt[(size_t)(h*64+sr)*NL + kt + sk];

    for (int it = 0; it < 16; it++) {
        __syncthreads();
        *(uint4*)&Ks[sr][sk] = ka;
        *(uint4*)&Vs[sr][sk] = va;
        __syncthreads();
        if (it < 15) {
            int kn = kt + 64;
            ka = *(const uint4*)&Kb[(size_t)(kn+sr)*512 + h*64 + sk];
            va = *(const uint4*)&Vt[(size_t)(h*64+sr)*NL + kn + sk];
        }
        #pragma unroll
        for (int nt = 0; nt < 4; nt++) {
            f32x4 s = {};
            __builtin_amdgcn_s_setprio(1);
            #pragma unroll
            for (int ks = 0; ks < 2; ks++) {
                bf16x8 kb = *(bf16x8*)&Ks[nt*16 + fm][ks*32 + fq*8];  // A: row=k_pos, k=d
                s = __builtin_amdgcn_mfma_f32_16x16x32_bf16(kb, qa[ks], s, 0, 0, 0);
            }
            __builtin_amdgcn_s_setprio(0);
            // s = S^T fragment: lane holds S[k_pos=(lane>>4)*4+i][q=lane&15]
            bf16x4 pb;
            #pragma unroll
            for (int i = 0; i < 4; i++) {
                hbf ph = __float2bfloat16(__expf(s[i] - 4.0f));
                pb[i] = *(short*)&ph;
                psum += __bfloat162float(ph);   // rounded-P sum, consistent with PV input
            }
            // pb is exactly the B-frag of 16x16x16: col=lane&15=q, k=(lane>>4)*4+j
            __builtin_amdgcn_s_setprio(1);
            #pragma unroll
            for (int ntd = 0; ntd < 4; ntd++) {
                bf16x4 va4 = *(bf16x4*)&Vs[ntd*16 + fm][nt*16 + fq*4];  // A: V^T[d][k]
                o[ntd] = __builtin_amdgcn_mfma_f32_16x16x16bf16_1k(va4, pb, o[ntd], 0, 0, 0);
            }
            __builtin_amdgcn_s_setprio(0);
        }
        kt += 64;
    }
    // fold the 4 fq groups (same q=fm): full row-sum of P for this q
    psum += __shfl_xor(psum, 16);
    psum += __shfl_xor(psum, 32);
    hbf* Op = op.p[skc];
    int orow = q0 + w*16 + fm;   // q
    #pragma unroll
    for (int ntd = 0; ntd < 4; ntd++) {
        hbf ov[4] __attribute__((aligned(8)));
        #pragma unroll
        for (int i = 0; i < 4; i++) ov[i] = __float2bfloat16(o[ntd][i]);
        *(uint2*)&Op[(size_t)orow*HH + h*64 + ntd*16 + fq*4] = *(uint2*)ov;
    }
    if (fq == 0)
        lsum[(size_t)(skc*4 + h)*NL + q0 + w*16 + fm] = psum;
}

// exact merge: O = sum_c Oc / sum_c lc — vectorized: 8 rows/block, bf16x8 per thread
__global__ __launch_bounds__(256) void amerge_k(OPtrs op, const float* __restrict__ lsum,
                                                hbf* __restrict__ aob) {
    int t = threadIdx.x;
    int row = blockIdx.x*8 + (t >> 5);
    int d8 = (t & 31) << 3;
    int h = d8 >> 6;
    float L = 0.0f;
    #pragma unroll
    for (int c = 0; c < 4; c++) L += lsum[(size_t)(c*4 + h)*NL + row];
    float inv = 1.0f / L;
    float s[8] = {};
    #pragma unroll
    for (int c = 0; c < 4; c++) {
        bf16x8 v = *(const bf16x8*)&op.p[c][(size_t)row*HH + d8];
        #pragma unroll
        for (int j = 0; j < 8; j++) {
            short tv = v[j]; hbf hv; *(short*)&hv = tv;
            s[j] += __bfloat162float(hv);
        }
    }
    hbf out[8];
    #pragma unroll
    for (int j = 0; j < 8; j++) out[j] = __float2bfloat16(s[j] * inv);
    *(uint4*)&aob[(size_t)row*HH + d8] = *(uint4*)out;
}

// ---------------- layernorm + pool partials: wave-per-row, barrier- and atomic-free ----------------
// 1024 blocks x 4 waves; each wave owns one row (4 elems/lane, float4). part is [512][2048]:
// slot = r&511, col = (r>>9)*256 + c -> every (row, col) unique => plain stores.
__global__ __launch_bounds__(256) void ln_k(const float* __restrict__ X,
                    const float* __restrict__ g, const float* __restrict__ b,
                    float* __restrict__ part) {
    int t = threadIdx.x;
    int w = t >> 6, lane = t & 63;
    int r = blockIdx.x*4 + w;
    int c4 = lane << 2;
    float4 v = *(const float4*)&X[(size_t)r*HH + c4];
    float s = v.x + v.y + v.z + v.w;
    #pragma unroll
    for (int o = 1; o < 64; o <<= 1) s += __shfl_xor(s, o);
    float mean = s * (1.0f/256.0f);
    float d0 = v.x - mean, d1 = v.y - mean, d2 = v.z - mean, d3 = v.w - mean;
    float q = d0*d0 + d1*d1 + d2*d2 + d3*d3;
    #pragma unroll
    for (int o = 1; o < 64; o <<= 1) q += __shfl_xor(q, o);
    float rstd = rsqrtf(q * (1.0f/256.0f) + 1e-5f);
    float4 gv = *(const float4*)&g[c4];
    float4 bv = *(const float4*)&b[c4];
    float4 out;
    out.x = (d0 * rstd * gv.x + bv.x) * (1.0f/512.0f);
    out.y = (d1 * rstd * gv.y + bv.y) * (1.0f/512.0f);
    out.z = (d2 * rstd * gv.z + bv.z) * (1.0f/512.0f);
    out.w = (d3 * rstd * gv.w + bv.w) * (1.0f/512.0f);
    *(float4*)&part[(size_t)(r & 511)*2048 + (r >> 9)*HH + c4] = out;
}

// reduce: 64 blocks, coalesced 32-consecutive-element reads, LDS fold of 8 slot-groups.
// Sum order per element: strictly ascending slot (= ascending r&511 within batch).
__global__ __launch_bounds__(256) void reduce_k(const float* __restrict__ part,
                                                float* __restrict__ pooled) {
    __shared__ float red[8][33];
    int b = blockIdx.x, t = threadIdx.x;
    int e = b*32 + (t & 31);
    int pg = t >> 5;                       // 0..7, slots pg*64 .. pg*64+63
    float s = 0.0f;
    #pragma unroll 16
    for (int p = 0; p < 64; p++)
        s += part[(size_t)(pg*64 + p)*2048 + e];
    red[pg][t & 31] = s;
    __syncthreads();
    if (t < 32) {
        float r = 0.0f;
        #pragma unroll
        for (int j = 0; j < 8; j++) r += red[j][t];
        pooled[b*32 + t] = r;
    }
}

// ---------------- heads: wave per output, bf16 transposed weights, 4 elems/lane ----------------
__global__ __launch_bounds__(256) void heads_k(const float* __restrict__ pooled,
        const hbf* __restrict__ hwt,
        const float* cbh, const float* hb, const float* tb, const float* p1b,
        const float* p2b, const float* db, const float* sb, float* __restrict__ out)
{
    int idx = blockIdx.x*4 + (threadIdx.x >> 6);
    int lane = threadIdx.x & 63;
    if (idx >= NOUT) return;
    int b = idx / 1552, j = idx - b*1552;
    const float* bi; int col;
    if (j < 1)         { bi = cbh; col = j;        }
    else if (j < 5)    { bi = hb;  col = j - 1;    }
    else if (j < 8)    { bi = tb;  col = j - 5;    }
    else if (j < 520)  { bi = p1b; col = j - 8;    }
    else if (j < 1032) { bi = p2b; col = j - 520;  }
    else if (j < 1544) { bi = db;  col = j - 1032; }
    else               { bi = sb;  col = j - 1544; }
    const float* pl = pooled + b*HH;
    const hbf* wr = hwt + (size_t)j*256;
    int k4 = lane * 4;
    float4 pv = *(const float4*)&pl[k4];
    short4 wv = *(const short4*)&wr[k4];
    hbf w0, w1, w2, w3;
    *(short*)&w0 = wv.x; *(short*)&w1 = wv.y; *(short*)&w2 = wv.z; *(short*)&w3 = wv.w;
    float s = pv.x*__bfloat162float(w0) + pv.y*__bfloat162float(w1)
            + pv.z*__bfloat162float(w2) + pv.w*__bfloat162float(w3);
    #pragma unroll
    for (int o = 32; o > 0; o >>= 1) s += __shfl_down(s, o);
    if (lane == 0) out[idx] = s + bi[col];
}

// ---------------- launcher ----------------
extern "C" void kernel_launch(void* const* d_in, const int* in_sizes, int n_in,
                              void* d_out, int out_size, void* d_ws, size_t ws_size,
                              hipStream_t stream)
{
    (void)in_sizes; (void)n_in; (void)out_size; (void)ws_size;
    const float* x      = (const float*)d_in[0];
    const int*   ei     = (const int*)  d_in[1];
    const float* W_init = (const float*)d_in[2];
    const float* b_init = (const float*)d_in[3];
    const float* g1W = (const float*)d_in[4];
    const float* g1b = (const float*)d_in[5];
    const float* g2W = (const float*)d_in[6];
    const float* g2b = (const float*)d_in[7];
    const float* inW = (const float*)d_in[8];
    const float* cW  = (const float*)d_in[9];
    const float* cb  = (const float*)d_in[10];
    const float* xpW = (const float*)d_in[11];
    const float* dtW = (const float*)d_in[12];
    const float* dtb = (const float*)d_in[13];
    const float* Alog= (const float*)d_in[14];
    const float* Dp  = (const float*)d_in[15];
    const float* outW= (const float*)d_in[16];
    const float* Wq  = (const float*)d_in[17];
    const float* bq  = (const float*)d_in[18];
    const float* Wk  = (const float*)d_in[19];
    const float* bk  = (const float*)d_in[20];
    const float* Wv  = (const float*)d_in[21];
    const float* bv  = (const float*)d_in[22];
    const float* Wo  = (const float*)d_in[23];
    const float* bo  = (const float*)d_in[24];
    const float* fusW= (const float*)d_in[25];
    const float* fusb= (const float*)d_in[26];
    const float* lng = (const float*)d_in[27];
    const float* lnb = (const float*)d_in[28];
    const float* cwp = (const float*)d_in[29];
    const float* cbp = (const float*)d_in[30];
    const float* hwp = (const float*)d_in[31];
    const float* hbp = (const float*)d_in[32];
    const float* twp = (const float*)d_in[33];
    const float* tbp = (const float*)d_in[34];
    const float* p1w = (const float*)d_in[35];
    const float* p1b = (const float*)d_in[36];
    const float* p2w = (const float*)d_in[37];
    const float* p2b = (const float*)d_in[38];
    const float* dwp = (const float*)d_in[39];
    const float* dbp = (const float*)d_in[40];
    const float* swp = (const float*)d_in[41];
    const float* sbp = (const float*)d_in[42];

    float* fw = (float*)d_ws;
    int* iw = (int*)(fw + O_INT);
    int* cnt = iw;                      // 4096 in-degree counters (zeroed by prep)
    int* csr = (int*)(fw + O_XC);       // 4096*64 bucket CSR; region reused by `fused` later

    hbf* wt   = (hbf*)(fw + O_WT);
    hbf* xb   = (hbf*)(fw + O_XB);
    hbf* h0b  = (hbf*)(fw + O_H0B);   // h0b, then h1b (reuse)
    hbf* h2b  = (hbf*)(fw + O_H2B);
    hbf* xcb  = (hbf*)(fw + O_XCB);
    hbf* dtab = (hbf*)(fw + O_DTAB);
    hbf* xzb  = (hbf*)(fw + O_XZB);
    hbf* yb   = (hbf*)(fw + O_Y);
    hbf* aob  = (hbf*)(fw + O_Y);
    hbf* catb = (hbf*)(fw + O_CATB);
    hbf* qkB  = (hbf*)(fw + O_QKB);
    hbf* vtB  = (hbf*)(fw + O_VTB);
    hbf* aggb = (hbf*)(fw + O_MBUF);  // gcn aggregation scratch (bf16)
    float* fused = fw + O_XC;         // live only after gathers are done
    float* b768 = fw + O_B768;
    float* part = fw + O_PART;
    hbf* hwt  = (hbf*)(fw + O_HWT);

    float* scanP  = fw + O_MBUF;
    float* scanHl = fw + O_QK;
    float* scanHst= fw + O_HST;
    float* lsum   = fw + O_HST;          // Hst dead after scan3

    OPtrs op;
    op.p[0] = (hbf*)(fw + O_MBUF);
    op.p[1] = (hbf*)(fw + O_MBUF + 524288);
    op.p[2] = (hbf*)(fw + O_DELTA);
    op.p[3] = (hbf*)(fw + O_DELTA + 524288);

    hbf* WtInit  = wt + 0;
    hbf* WtG1    = wt + 8192;
    hbf* WtG2    = wt + 73728;
    hbf* WtXp    = wt + 139264;
    hbf* WtDt    = wt + 155648;
    hbf* WtOut   = wt + 172032;
    hbf* WtInQKV = wt + 303104;
    hbf* WtO     = wt + 761856;
    hbf* WtFus   = wt + 827392;

    WSrc wsrc;
    wsrc.p[0]=W_init; wsrc.p[1]=g1W; wsrc.p[2]=g2W; wsrc.p[3]=xpW; wsrc.p[4]=dtW;
    wsrc.p[5]=outW; wsrc.p[6]=inW; wsrc.p[7]=Wq; wsrc.p[8]=Wk; wsrc.p[9]=Wv;
    wsrc.p[10]=Wo; wsrc.p[11]=fusW; wsrc.p[12]=p1w; wsrc.p[13]=p2w; wsrc.p[14]=dwp;
    HSrc4 hsrc;
    hsrc.p[0]=cwp; hsrc.p[1]=hwp; hsrc.p[2]=twp; hsrc.p[3]=swp;
    prep_k<<<PREP_BLKS,256,0,stream>>>(wsrc, wt, hwt, x, xb, bq, bk, bv, b768,
                                       part, cnt, hsrc);

    // graph prep: single bucket-CSR kernel
    bucket_k<<<256,256,0,stream>>>(ei, cnt, csr);

    // h0 = relu(x @ W_init + b_init) -> bf16
    mg_k<1,1><<<dim3(128,8),256,0,stream>>>((const unsigned short*)xb, (const unsigned short*)WtInit,
        b_init, h0b, 256, nullptr, nullptr, nullptr, 0, NL, 32, 256);
    // gcn1 reassociated: agg = A_hat h0 (bf16), then h1 = relu(agg @ W1 + b1)
    gather_k<<<512,256,0,stream>>>(h0b, csr, cnt, aggb);
    mg_k<1,1><<<dim3(128,8),256,0,stream>>>((const unsigned short*)aggb, (const unsigned short*)WtG1,
        g1b, h0b, 256, nullptr, nullptr, nullptr, 0, NL, 256, 256);
    // gcn2: agg = A_hat h1, then h2 = relu(agg @ W2 + b2) -> fp32 h2 + bf16 h2b + catb[0:256]
    gather_k<<<512,256,0,stream>>>(h0b, csr, cnt, aggb);
    mg_k<1,6><<<dim3(128,8),256,0,stream>>>((const unsigned short*)aggb, (const unsigned short*)WtG2,
        g2b, fw+O_H2, 256, h2b, catb, nullptr, 0, NL, 256, 256);

    // fused in_proj + QKV (N=1792): xzb | qkB (Q scaled) | vtB (transposed)
    mg_k<0,5><<<dim3(128,56),256,0,stream>>>((const unsigned short*)h2b, (const unsigned short*)WtInQKV,
        b768, xzb, 1024, qkB, vtB, nullptr, 0, NL, 256, 1792);

    // mamba
    conv_k<<<1024,256,0,stream>>>(xzb, cW, cb, xcb);
    mg_k<0,4><<<dim3(128,1),256,0,stream>>>((const unsigned short*)xcb, (const unsigned short*)WtXp,
        nullptr, fw+O_PROJ, 32, dtab, nullptr, nullptr, 0, NL, 512, 32);
    mg_k<2,0><<<dim3(128,16),256,0,stream>>>((const unsigned short*)dtab, (const unsigned short*)WtDt,
        dtb, fw+O_DELTA, 512, nullptr, nullptr, nullptr, 0, NL, 32, 512);
    scan1_k<<<512,256,0,stream>>>(fw+O_DELTA, xcb, fw+O_PROJ, Alog, scanP, scanHl);
    scan2t_k<<<256,256,0,stream>>>(scanP, scanHl, scanHst);
    scan3_k<<<512,256,0,stream>>>(fw+O_DELTA, xcb, fw+O_PROJ, Alog, scanHst, Dp, xzb, yb);
    mg_k<0,1><<<dim3(128,8),256,0,stream>>>((const unsigned short*)yb, (const unsigned short*)WtOut,
        nullptr, catb + 256, 768, nullptr, nullptr, nullptr, 0, NL, 512, 256);

    // attention (split-K 4)
    attn_part_k<<<dim3(32,4,4),512,0,stream>>>((const unsigned short*)qkB,
        (const unsigned short*)vtB, op, lsum);
    amerge_k<<<512,256,0,stream>>>(op, lsum, aob);
    mg_k<0,1><<<dim3(128,8),256,0,stream>>>((const unsigned short*)aob, (const unsigned short*)WtO,
        bo, catb + 512, 768, nullptr, nullptr, nullptr, 0, NL, 256, 256);

    // fuse + residual + LN(+pool partials) + reduce + heads
    mg_k<1,0><<<dim3(128,8),256,0,stream>>>((const unsigned short*)catb, (const unsigned short*)WtFus,
        fusb, fused, 256, nullptr, nullptr, fw+O_H2, 256, NL, 768, 256);
    ln_k<<<1024,256,0,stream>>>(fused, lng, lnb, part);
    reduce_k<<<64,256,0,stream>>>(part, fw+O_POOL);
    heads_k<<<(NOUT+3)/4,256,0,stream>>>(fw+O_POOL, hwt, cbp,hbp,tbp,p1b,p2b,dbp,sbp,
                                         (float*)d_out);
}

// Round 16
// 308.220 us; speedup vs baseline: 1.0095x; 1.0095x over previous
//
#include <hip/hip_runtime.h>
#include <hip/hip_bf16.h>
#include <math.h>

typedef __hip_bfloat16 hbf;
typedef short bf16x8 __attribute__((ext_vector_type(8)));
typedef short bf16x4 __attribute__((ext_vector_type(4)));
typedef float f32x4 __attribute__((ext_vector_type(4)));

// ---------------- problem constants ----------------
constexpr int NL  = 4096;
constexpr int HH  = 256;
constexpr int NE  = 8192;
constexpr int DIc = 512;
constexpr int DSc = 8;
constexpr int CLc = 16;    // scan chunk length (256 chunks)
constexpr int NOUT = 12416;

// ---------------- workspace layout (float offsets) ----------------
constexpr size_t O_MBUF  = 0;         // 1048576  agg bf16; scan P; attn op0/op1(bf16)
constexpr size_t O_QK    = 1048576;   // 1048576  scan Hl (temp)
constexpr size_t O_H2    = 2097152;   // 1048576  h2 fp32 (live to fus resid)
constexpr size_t O_CATB  = 3145728;   // 1572864  catb bf16 [NL][768]
constexpr size_t O_XZB   = 4718592;   // 2097152  xzb bf16 [NL][1024]
constexpr size_t O_XC    = 6815744;   // 2097152  csr (early phase) THEN fused fp32 (epilogue)
constexpr size_t O_DELTA = 8912896;   // 2097152  delta; attn op2/op3(bf16) after scan3
constexpr size_t O_PROJ  = 11010048;  // 131072   proj fp32
constexpr size_t O_HST   = 11141120;  // 1048576  Hst; lsum after scan3
constexpr size_t O_Y     = 12189696;  // 1048576  yb bf16; aob bf16
constexpr size_t O_POOL  = 13238272;  // 2048
constexpr size_t O_DINV  = 13240320;  // 4096 (unused, kept for layout stability)
constexpr size_t O_B768  = 13244416;  // 768
constexpr size_t O_INT   = 13245184;  // 81928 ints (cnt 4096 here)
constexpr size_t O_WT    = 13327112;  // 512000
constexpr size_t O_XB    = 13839112;  // 65536
constexpr size_t O_H0B   = 13904648;  // 524288  h0b, then h1b (reuse)
constexpr size_t O_H2B   = 14428936;  // 524288
constexpr size_t O_XCB   = 14953224;  // 1048576
constexpr size_t O_DTAB  = 16001800;  // 65536
constexpr size_t O_QKB   = 16067584;  // 1048576  qkB bf16 [NL][512]
constexpr size_t O_VTB   = 17116160;  // 524288   vtB bf16 [256][NL]
constexpr size_t O_HWT   = 17902592;  // transposed head weights [1552][256] bf16 (397312)
constexpr size_t O_PART  = 18350080;  // 1048576  ln partial pools [512][2048] (atomic-free)

// ---------------- transpose-cast tables ----------------
constexpr int NW = 12;
__device__ __constant__ int wc_cum[NW+1] = {
    0, 8192, 73728, 139264, 155648, 172032, 303104, 565248,
    630784, 696320, 761856, 827392, 1024000 };
constexpr int NT = 15;
__device__ __constant__ int tc_cum[NT+1] = {
    0, 8, 72, 136, 152, 168, 296, 552, 616, 680, 744, 808, 1000, 1128, 1256, 1384 };
__device__ __constant__ int tc_kt[NT] = {1,8,8,16,1,16,8,8,8,8,8,24,8,8,8};
__device__ __constant__ int tc_K [NT] = {32,256,256,512,16,512,256,256,256,256,256,768,256,256,256};
__device__ __constant__ int tc_N [NT] = {256,256,256,32,512,256,1024,256,256,256,256,256,512,512,512};
__device__ __constant__ int tc_Kp[NT] = {32,256,256,512,32,512,256,256,256,256,256,768,256,256,256};
__device__ __constant__ int hw_off[3] = {2048, 133120, 264192};  // j=8,520,1032 (x256) in hwt

struct WSrc { const float* p[NT]; };
struct HSrc4 { const float* p[4]; };  // cw, hw, tw, sw (small head cols)
struct OPtrs { hbf* p[4]; };

// prep: tiled weight transposes (blocks < TTILES) + misc tail
constexpr int TTILES = 1384;
constexpr int M_X = 131072;
constexpr int M_B = M_X + 768;        // 131840
constexpr int M_P = M_B + 1048576;    // 1180416 (part zero, 4 MB)
constexpr int M_C = M_P + 4096;       // 1184512
constexpr int M_H = M_C + 4096;       // 1188608
constexpr int PREP_BLKS = TTILES + M_H/256;   // 1384 + 4643 = 6027

__global__ __launch_bounds__(256) void prep_k(WSrc ws, hbf* __restrict__ wt,
        hbf* __restrict__ hwt,
        const float* __restrict__ x, hbf* __restrict__ xb,
        const float* __restrict__ bq, const float* __restrict__ bk,
        const float* __restrict__ bv,
        float* __restrict__ b768, float* __restrict__ part, int* __restrict__ cnt,
        HSrc4 hs) {
    __shared__ float T[32][33];
    int bid = blockIdx.x, t = threadIdx.x;
    if (bid < TTILES) {
        int lo = 0, hi = NT-1;
        while (lo < hi) { int mid = (lo+hi+1)>>1; if (bid >= tc_cum[mid]) lo = mid; else hi = mid-1; }
        int lt = bid - tc_cum[lo];
        int ktl = tc_kt[lo];
        int tn = lt / ktl, tk = lt - tn*ktl;
        int K = tc_K[lo], N = tc_N[lo], Kp = tc_Kp[lo];
        const float* src = ws.p[lo];
        int r = t >> 3, c4 = (t & 7) << 2;
        int k0 = tk*32, n0 = tn*32;
        float4 v = make_float4(0.f, 0.f, 0.f, 0.f);
        if (k0 + r < K)
            v = *(const float4*)&src[(size_t)(k0+r)*N + n0 + c4];
        T[r][c4]   = v.x; T[r][c4+1] = v.y; T[r][c4+2] = v.z; T[r][c4+3] = v.w;
        __syncthreads();
        hbf o[4] __attribute__((aligned(8)));
        #pragma unroll
        for (int j = 0; j < 4; j++) o[j] = __float2bfloat16(T[c4+j][r]);
        hbf* dstp = (lo < NW) ? (wt + wc_cum[lo]) : (hwt + hw_off[lo - NW]);
        *(uint2*)&dstp[(size_t)(n0+r)*Kp + k0 + c4] = *(uint2*)o;
    } else {
        int idx = (bid - TTILES)*256 + t;
        if (idx < M_X) {
            xb[idx] = __float2bfloat16(x[idx]);
        } else if (idx < M_B) {
            int i = idx - M_X;
            b768[i] = (i < 256) ? bq[i] : (i < 512 ? bk[i-256] : bv[i-512]);
        } else if (idx < M_P) {
            part[idx - M_B] = 0.0f;
        } else if (idx < M_C) {
            cnt[idx - M_P] = 0;
        } else {
            int i = idx - M_C;
            int jj = i >> 8, k = i & 255;
            int j = (jj < 8) ? jj : (1536 + jj);
            const float* sp; int col, nc;
            if (j < 1)       { sp = hs.p[0]; col = j;        nc = 1; }
            else if (j < 5)  { sp = hs.p[1]; col = j - 1;    nc = 4; }
            else if (j < 8)  { sp = hs.p[2]; col = j - 5;    nc = 3; }
            else             { sp = hs.p[3]; col = j - 1544; nc = 8; }
            hwt[(size_t)j*256 + k] = __float2bfloat16(sp[(size_t)k*nc + col]);
        }
    }
}

// ---------------- graph prep: single-kernel bucket CSR (cap 64/node, 12-sigma safe + guarded) ----------------
__global__ void bucket_k(const int* __restrict__ ei, int* __restrict__ cnt,
                         int* __restrict__ csr) {
    int i = blockIdx.x*256 + threadIdx.x;
    int b = i >> 13, e = i & 8191;
    int src = ei[b*2*NE + e]      + (b << 9);
    int dst = ei[b*2*NE + NE + e] + (b << 9);
    int slot = atomicAdd(&cnt[dst], 1);
    if (slot < 64) csr[(dst << 6) + slot] = src;
}

// gather: 8 nodes/block, 32 lanes x bf16x8 per node (16B/lane loads, 8 independent
// latency chains per block). Accumulation order bit-identical to 2-acc even/odd scheme.
__global__ __launch_bounds__(256) void gather_k(const hbf* __restrict__ m,
                        const int* __restrict__ csr, const int* __restrict__ cnt,
                        hbf* __restrict__ outb) {
    __shared__ int   sidx[8][64];
    __shared__ float sdv[8][64];
    int t = threadIdx.x;
    int ni = t >> 5, l32 = t & 31;
    int n = blockIdx.x*8 + ni;
    int cn = min(cnt[n], 64);
    for (int e = l32; e < cn; e += 32) {
        int s = csr[(n << 6) + e];
        sidx[ni][e] = s;
        sdv[ni][e]  = rsqrtf(1.0f + (float)min(cnt[s], 64));
    }
    __syncthreads();
    float dn = rsqrtf(1.0f + (float)cn);
    int c8 = l32 << 3;
    float a0[8], a1[8];
    {
        bf16x8 v = *(const bf16x8*)&m[(size_t)n*HH + c8];
        #pragma unroll
        for (int j = 0; j < 8; j++) {
            short tv = v[j]; hbf hv; *(short*)&hv = tv;
            a0[j] = __bfloat162float(hv) * dn;
            a1[j] = 0.0f;
        }
    }
    int e = 0;
    for (; e + 1 < cn; e += 2) {
        bf16x8 v0 = *(const bf16x8*)&m[(size_t)sidx[ni][e]  *HH + c8];
        bf16x8 v1 = *(const bf16x8*)&m[(size_t)sidx[ni][e+1]*HH + c8];
        float d0 = sdv[ni][e], d1 = sdv[ni][e+1];
        #pragma unroll
        for (int j = 0; j < 8; j++) {
            short t0 = v0[j]; hbf h0; *(short*)&h0 = t0;
            short t1 = v1[j]; hbf h1; *(short*)&h1 = t1;
            a0[j] += __bfloat162float(h0) * d0;
            a1[j] += __bfloat162float(h1) * d1;
        }
    }
    if (e < cn) {
        bf16x8 v0 = *(const bf16x8*)&m[(size_t)sidx[ni][e]*HH + c8];
        float d0 = sdv[ni][e];
        #pragma unroll
        for (int j = 0; j < 8; j++) {
            short t0 = v0[j]; hbf h0; *(short*)&h0 = t0;
            a0[j] += __bfloat162float(h0) * d0;
        }
    }
    hbf out[8] __attribute__((aligned(16)));
    #pragma unroll
    for (int j = 0; j < 8; j++) out[j] = __float2bfloat16((a0[j] + a1[j]) * dn);
    *(uint4*)&outb[(size_t)n*HH + c8] = *(uint4*)out;
}

// ---------------- bf16 MFMA GEMM: 256 threads / 4 waves, 32x32 tile, BK=64 ----------------
// OUTM: 0 fp32, 1 bf16, 5 fused in_proj+QKV, 6 gcn2 triple-out (fp32+bf16+catb)
// ACT: 0 none, 1 relu, 2 softplus
template<int ACT, int OUTM>
__global__ __launch_bounds__(256) void mg_k(const unsigned short* __restrict__ A,
        const unsigned short* __restrict__ Bt, const float* __restrict__ bias,
        void* __restrict__ Cp, int ldc, void* __restrict__ Cp2, void* __restrict__ Cp3,
        const float* __restrict__ resid, int ldr, int M, int K, int N)
{
    __shared__ __align__(16) unsigned short Asm[2][32][40];
    __shared__ __align__(16) unsigned short Bsm[2][32][40];
    int t = threadIdx.x;
    int lane = t & 63, w = t >> 6;              // 4 waves
    int wr = (w & 1) * 16, wc = (w >> 1) * 16;  // wave quadrant
    int row0 = blockIdx.x * 32, col0 = blockIdx.y * 32;
    int sr = t >> 3, sk8 = (t & 7) * 8;         // staging: 32 rows x 64k, 1 uint4/thread
    f32x4 acc = {};
    int fr = lane & 15, fq8 = (lane >> 4) * 8;

    uint4 zz = make_uint4(0u,0u,0u,0u);
    uint4 ra = zz, rb = zz;
    if (sk8 < K) {
        ra = *(const uint4*)&A[(size_t)(row0+sr)*K + sk8];
        rb = *(const uint4*)&Bt[(size_t)(col0+sr)*K + sk8];
    }

    for (int k0 = 0; k0 < K; k0 += 64) {
        __syncthreads();
        *(uint4*)&Asm[sk8>>5][sr][sk8 & 31] = ra;
        *(uint4*)&Bsm[sk8>>5][sr][sk8 & 31] = rb;
        __syncthreads();
        int kn = k0 + 64;
        if (kn < K) {
            ra = rb = zz;
            if (kn + sk8 < K) {
                ra = *(const uint4*)&A[(size_t)(row0+sr)*K + kn + sk8];
                rb = *(const uint4*)&Bt[(size_t)(col0+sr)*K + kn + sk8];
            }
        }
        #pragma unroll
        for (int ks = 0; ks < 2; ks++) {
            bf16x8 a = *(bf16x8*)&Asm[ks][wr + fr][fq8];
            bf16x8 b = *(bf16x8*)&Bsm[ks][wc + fr][fq8];
            acc = __builtin_amdgcn_mfma_f32_16x16x32_bf16(a, b, acc, 0, 0, 0);
        }
    }

    int fc = lane & 15, frq = (lane >> 4) * 4;
    if constexpr (OUTM == 5) {
        if (col0 < 1024) {
            int col = col0 + wc + fc;
            #pragma unroll
            for (int i = 0; i < 4; i++) {
                int row = row0 + wr + frq + i;
                ((hbf*)Cp)[(size_t)row*1024 + col] = __float2bfloat16(acc[i]);
            }
        } else if (col0 < 1536) {
            int gcol = col0 + wc + fc;
            int col = gcol - 1024;
            float bvv = bias[col];
            float sc = (col < 256) ? 0.125f : 1.0f;
            #pragma unroll
            for (int i = 0; i < 4; i++) {
                int row = row0 + wr + frq + i;
                ((hbf*)Cp2)[(size_t)row*512 + col] = __float2bfloat16((acc[i] + bvv) * sc);
            }
        } else {
            __shared__ __align__(16) unsigned short Ts[32][48];
            int gcol = col0 + wc + fc;
            float bvv = bias[gcol - 1024];
            #pragma unroll
            for (int i = 0; i < 4; i++)
                *(hbf*)&Ts[wc + fc][wr + frq + i] = __float2bfloat16(acc[i] + bvv);
            __syncthreads();
            if (t < 128) {
                int c = t >> 2, rs = (t & 3) * 8;
                *(uint4*)((hbf*)Cp3 + (size_t)(col0 - 1536 + c)*NL + row0 + rs) = *(uint4*)&Ts[c][rs];
            }
        }
    } else if constexpr (OUTM == 6) {
        int col = col0 + wc + fc;
        float bvv = bias[col];
        #pragma unroll
        for (int i = 0; i < 4; i++) {
            int row = row0 + wr + frq + i;
            float v = fmaxf(acc[i] + bvv, 0.0f);
            ((float*)Cp)[(size_t)row*HH + col] = v;
            hbf hv = __float2bfloat16(v);
            ((hbf*)Cp2)[(size_t)row*HH + col] = hv;
            ((hbf*)Cp3)[(size_t)row*768 + col] = hv;
        }
    } else {
        int col = col0 + wc + fc;
        if (col < N) {
            float bvv = bias ? bias[col] : 0.0f;
            #pragma unroll
            for (int i = 0; i < 4; i++) {
                int row = row0 + wr + frq + i;
                float v = acc[i] + bvv;
                if (ACT == 1) v = fmaxf(v, 0.0f);
                if (ACT == 2) v = (v > 20.0f) ? v : log1pf(expf(v));
                if (resid) v += resid[(size_t)row*ldr + col];
                if (OUTM == 0) ((float*)Cp)[(size_t)row*ldc + col] = v;
                else           ((hbf*)Cp)[(size_t)row*ldc + col] = __float2bfloat16(v);
            }
        }
    }
}

// ---------------- proj GEMM: M=4096 K=512 N=32 — 256 blocks x 16 rows, single-stage LDS ----------------
// Old shape was 128 blocks (0.5/CU, half the GPU idle) x 8 barrier-separated K-iters.
// Here: stage A-panel (16x512) + full WtXp (32x512) once; 4 waves split (col-half x K-half);
// each wave runs one unchained 8-MFMA accumulation; K-halves combine via 2KB LDS.
// Sum order: (K 0..255) + (K 256..511) — same f32 reassociation class as attn split-K.
__global__ __launch_bounds__(256) void mgp_k(const unsigned short* __restrict__ A,
        const unsigned short* __restrict__ Bt, float* __restrict__ proj,
        hbf* __restrict__ dtab)
{
    __shared__ __align__(16) unsigned short As[16][520];
    __shared__ __align__(16) unsigned short Bs[32][520];
    __shared__ float red[2][16][17];
    int t = threadIdx.x, lane = t & 63, w = t >> 6;
    int r0 = blockIdx.x * 16;
    #pragma unroll
    for (int i = 0; i < 4; i++) {
        int idx = t + i*256;
        int row = idx >> 6, k8 = (idx & 63) << 3;
        *(uint4*)&As[row][k8] = *(const uint4*)&A[(size_t)(r0+row)*512 + k8];
    }
    #pragma unroll
    for (int i = 0; i < 8; i++) {
        int idx = t + i*256;
        int row = idx >> 6, k8 = (idx & 63) << 3;
        *(uint4*)&Bs[row][k8] = *(const uint4*)&Bt[(size_t)row*512 + k8];
    }
    __syncthreads();
    int fm = lane & 15, fq8 = (lane >> 4) * 8;
    int ch = w & 1, kh = w >> 1;
    f32x4 acc = {};
    #pragma unroll
    for (int ks = 0; ks < 8; ks++) {
        bf16x8 a = *(bf16x8*)&As[fm][kh*256 + ks*32 + fq8];
        bf16x8 b = *(bf16x8*)&Bs[ch*16 + fm][kh*256 + ks*32 + fq8];
        acc = __builtin_amdgcn_mfma_f32_16x16x32_bf16(a, b, acc, 0, 0, 0);
    }
    int fc = lane & 15, frq = (lane >> 4) * 4;
    if (kh == 1) {
        #pragma unroll
        for (int i = 0; i < 4; i++) red[ch][frq + i][fc] = acc[i];
    }
    __syncthreads();
    if (kh == 0) {
        #pragma unroll
        for (int i = 0; i < 4; i++) {
            int row = r0 + frq + i;
            int col = ch*16 + fc;
            float v = acc[i] + red[ch][frq + i][fc];
            proj[(size_t)row*32 + col] = v;
            dtab[(size_t)row*32 + col] = __float2bfloat16((ch == 0) ? v : 0.0f);
        }
    }
}

// ---------------- mamba: conv + silu, vectorized bf16x8 (8 outputs/thread) ----------------
__global__ __launch_bounds__(256) void conv_k(const hbf* __restrict__ xzb,
                       const float* __restrict__ cW,
                       const float* __restrict__ cb, hbf* __restrict__ xcb) {
    int i = blockIdx.x*256 + threadIdx.x;      // 262144 threads: l = i>>6, d8 = (i&63)*8
    int l = i >> 6, d8 = (i & 63) << 3;
    float acc[8];
    {
        float4 c0 = *(const float4*)&cb[d8];
        float4 c1 = *(const float4*)&cb[d8+4];
        acc[0]=c0.x; acc[1]=c0.y; acc[2]=c0.z; acc[3]=c0.w;
        acc[4]=c1.x; acc[5]=c1.y; acc[6]=c1.z; acc[7]=c1.w;
    }
    float4 cw4[8];
    #pragma unroll
    for (int j = 0; j < 8; j++) cw4[j] = *(const float4*)&cW[(d8+j)*4];
    #pragma unroll
    for (int k = 0; k < 4; k++) {
        int ls = l - 3 + k;
        if (ls < 0) continue;
        bf16x8 v = *(const bf16x8*)&xzb[(size_t)ls*1024 + d8];
        #pragma unroll
        for (int j = 0; j < 8; j++) {
            short tv = v[j]; hbf hv; *(short*)&hv = tv;
            float wk = (k == 0) ? cw4[j].x : (k == 1) ? cw4[j].y : (k == 2) ? cw4[j].z : cw4[j].w;
            acc[j] += __bfloat162float(hv) * wk;
        }
    }
    hbf out[8];
    #pragma unroll
    for (int j = 0; j < 8; j++) {
        float r = acc[j] / (1.0f + __expf(-acc[j]));
        out[j] = __float2bfloat16(r);
    }
    *(uint4*)&xcb[(size_t)l*512 + d8] = *(uint4*)out;
}

// ---------------- mamba chunked scan (256 chunks x 16 steps) ----------------
__global__ __launch_bounds__(256) void scan1_k(const float* __restrict__ delta,
                        const hbf* __restrict__ xc, const float* __restrict__ proj,
                        const float* __restrict__ Alog,
                        float* __restrict__ P, float* __restrict__ Hl)
{
    int c = blockIdx.x >> 1;
    int d = ((blockIdx.x & 1) << 8) + threadIdx.x;
    float Ac[DSc], pr[DSc], h[DSc];
    #pragma unroll
    for (int s2 = 0; s2 < DSc; s2++) { Ac[s2] = -__expf(Alog[d*DSc+s2]); pr[s2]=1.0f; h[s2]=0.0f; }
    int l0 = c * CLc;
    for (int l = l0; l < l0 + CLc; l++) {
        float dl = delta[(size_t)l*DIc + d];
        float dx = dl * __bfloat162float(xc[(size_t)l*DIc + d]);
        const float* pb = proj + l*32 + 16;
        #pragma unroll
        for (int s2 = 0; s2 < DSc; s2++) {
            float a = __expf(dl * Ac[s2]);
            h[s2] = a*h[s2] + dx*pb[s2];
            pr[s2] *= a;
        }
    }
    #pragma unroll
    for (int s2 = 0; s2 < DSc; s2++) {
        P [(size_t)(c*DSc+s2)*DIc + d] = pr[s2];
        Hl[(size_t)(c*DSc+s2)*DIc + d] = h[s2];
    }
}

// coalesced middle scan: block = 16 consecutive series, LDS tile [256 chunks][16 series]
__global__ __launch_bounds__(256) void scan2t_k(const float* __restrict__ P,
                        const float* __restrict__ Hl, float* __restrict__ Hst) {
    __shared__ float Ps[256][17], Hs[256][17];
    int t = threadIdx.x, sg = blockIdx.x;
    int si = t & 15, cb = t >> 4;
    #pragma unroll
    for (int it = 0; it < 16; it++) {
        int c = it*16 + cb;
        size_t off = (size_t)c*4096 + sg*16 + si;
        Ps[c][si] = P[off];
        Hs[c][si] = Hl[off];
    }
    __syncthreads();
    int si2 = t >> 4, g = t & 15;
    int lane = t & 63;
    float Pg = 1.0f, Hg = 0.0f;
    #pragma unroll
    for (int j = 0; j < 16; j++) {
        int c = g*16 + j;
        float pc = Ps[c][si2], hc = Hs[c][si2];
        Hg = hc + pc*Hg;
        Pg = pc*Pg;
    }
    #pragma unroll
    for (int off = 1; off < 16; off <<= 1) {
        float Pp = __shfl(Pg, lane - off);
        float Hp = __shfl(Hg, lane - off);
        if (g >= off) { Hg = Hg + Pg*Hp; Pg = Pg*Pp; }
    }
    float carry = __shfl(Hg, lane - 1);
    if (g == 0) carry = 0.0f;
    float h = carry;
    #pragma unroll
    for (int j = 0; j < 16; j++) {
        int c = g*16 + j;
        float pc = Ps[c][si2], hc = Hs[c][si2];
        Hs[c][si2] = h;
        h = hc + pc*h;
    }
    __syncthreads();
    #pragma unroll
    for (int it = 0; it < 16; it++) {
        int c = it*16 + cb;
        Hst[(size_t)c*4096 + sg*16 + si] = Hs[c][si];
    }
}

__global__ __launch_bounds__(256) void scan3_k(const float* __restrict__ delta,
                        const hbf* __restrict__ xc, const float* __restrict__ proj,
                        const float* __restrict__ Alog, const float* __restrict__ Hst,
                        const float* __restrict__ Dp, const hbf* __restrict__ xzb,
                        hbf* __restrict__ Y)
{
    int c = blockIdx.x >> 1;
    int d = ((blockIdx.x & 1) << 8) + threadIdx.x;
    float Ac[DSc], h[DSc];
    #pragma unroll
    for (int s2 = 0; s2 < DSc; s2++) {
        Ac[s2] = -__expf(Alog[d*DSc+s2]);
        h[s2]  = Hst[(size_t)(c*DSc+s2)*DIc + d];
    }
    float dpv = Dp[d];
    int l0 = c * CLc;
    for (int l = l0; l < l0 + CLc; l++) {
        float dl = delta[(size_t)l*DIc + d];
        float xv = __bfloat162float(xc[(size_t)l*DIc + d]);
        float dx = dl * xv;
        const float* pb = proj + l*32 + 16;
        float y = 0.0f;
        #pragma unroll
        for (int s2 = 0; s2 < DSc; s2++) {
            float a = __expf(dl * Ac[s2]);
            h[s2] = a*h[s2] + dx*pb[s2];
            y += h[s2] * pb[8+s2];
        }
        float z = __bfloat162float(xzb[(size_t)l*1024 + 512 + d]);
        float sz = z / (1.0f + __expf(-z));
        Y[(size_t)l*DIc + d] = __float2bfloat16((y + dpv*xv) * sz);
    }
}

// ---------------- split-K(4) MFMA flash attention, TQ=128, constant-shift softmax ----------------
// Swapped-operand QK (S^T = mfma(K,Q)): lane's S fragment IS the PV B-operand fragment.
// lsum row-sum is lane-local f32 accumulation + 2 shfl_xor folds.
__global__ __launch_bounds__(512, 8) void attn_part_k(const unsigned short* __restrict__ QK,
                       const unsigned short* __restrict__ Vt,
                       OPtrs op, float* __restrict__ lsum)
{
    __shared__ __align__(16) unsigned short QPs[128][72];
    __shared__ __align__(16) unsigned short Ks[64][72];
    __shared__ __align__(16) unsigned short Vs[64][72];
    int t = threadIdx.x, lane = t & 63, w = t >> 6;
    int h = blockIdx.y, q0 = blockIdx.x * 128, skc = blockIdx.z;
    int fm = lane & 15, fq = lane >> 4;

    {
        int qr = t >> 2, qc = (t & 3) * 16;
        const unsigned short* src = &QK[(size_t)(q0+qr)*512 + h*64 + qc];
        *(uint4*)&QPs[qr][qc]     = *(const uint4*)&src[0];
        *(uint4*)&QPs[qr][qc + 8] = *(const uint4*)&src[8];
    }
    __syncthreads();
    bf16x8 qa[2];   // B-operand of S^T: col=lane&15 -> q, k=(lane>>4)*8+j -> head-dim d
    #pragma unroll
    for (int ks = 0; ks < 2; ks++)
        qa[ks] = *(bf16x8*)&QPs[w*16 + fm][ks*32 + fq*8];

    f32x4 o[4] = {};   // o^T: col=lane&15=q, row=(lane>>4)*4+i = d within subtile ntd
    float psum = 0.0f;
    int sr = t >> 3, sk = (t & 7) * 8;
    const unsigned short* Kb = QK + 256;
    int kt = skc * 1024;
    uint4 ka = *(const uint4*)&Kb[(size_t)(kt+sr)*512 + h*64 + sk];
    uint4 va = *(const uint4*)&Vt[(size_t)(h*64+sr)*NL + kt + sk];

    for (int it = 0; it < 16; it++) {
        __syncthreads();
        *(uint4*)&Ks[sr][sk] = ka;
        *(uint4*)&Vs[sr][sk] = va;
        __syncthreads();
        if (it < 15) {
            int kn = kt + 64;
            ka = *(const uint4*)&Kb[(size_t)(kn+sr)*512 + h*64 + sk];
            va = *(const uint4*)&Vt[(size_t)(h*64+sr)*NL + kn + sk];
        }
        #pragma unroll
        for (int nt = 0; nt < 4; nt++) {
            f32x4 s = {};
            __builtin_amdgcn_s_setprio(1);
            #pragma unroll
            for (int ks = 0; ks < 2; ks++) {
                bf16x8 kb = *(bf16x8*)&Ks[nt*16 + fm][ks*32 + fq*8];  // A: row=k_pos, k=d
                s = __builtin_amdgcn_mfma_f32_16x16x32_bf16(kb, qa[ks], s, 0, 0, 0);
            }
            __builtin_amdgcn_s_setprio(0);
            // s = S^T fragment: lane holds S[k_pos=(lane>>4)*4+i][q=lane&15]
            bf16x4 pb;
            #pragma unroll
            for (int i = 0; i < 4; i++) {
                hbf ph = __float2bfloat16(__expf(s[i] - 4.0f));
                pb[i] = *(short*)&ph;
                psum += __bfloat162float(ph);   // rounded-P sum, consistent with PV input
            }
            // pb is exactly the B-frag of 16x16x16: col=lane&15=q, k=(lane>>4)*4+j
            __builtin_amdgcn_s_setprio(1);
            #pragma unroll
            for (int ntd = 0; ntd < 4; ntd++) {
                bf16x4 va4 = *(bf16x4*)&Vs[ntd*16 + fm][nt*16 + fq*4];  // A: V^T[d][k]
                o[ntd] = __builtin_amdgcn_mfma_f32_16x16x16bf16_1k(va4, pb, o[ntd], 0, 0, 0);
            }
            __builtin_amdgcn_s_setprio(0);
        }
        kt += 64;
    }
    // fold the 4 fq groups (same q=fm): full row-sum of P for this q
    psum += __shfl_xor(psum, 16);
    psum += __shfl_xor(psum, 32);
    hbf* Op = op.p[skc];
    int orow = q0 + w*16 + fm;   // q
    #pragma unroll
    for (int ntd = 0; ntd < 4; ntd++) {
        hbf ov[4] __attribute__((aligned(8)));
        #pragma unroll
        for (int i = 0; i < 4; i++) ov[i] = __float2bfloat16(o[ntd][i]);
        *(uint2*)&Op[(size_t)orow*HH + h*64 + ntd*16 + fq*4] = *(uint2*)ov;
    }
    if (fq == 0)
        lsum[(size_t)(skc*4 + h)*NL + q0 + w*16 + fm] = psum;
}

// exact merge: O = sum_c Oc / sum_c lc — vectorized: 8 rows/block, bf16x8 per thread
__global__ __launch_bounds__(256) void amerge_k(OPtrs op, const float* __restrict__ lsum,
                                                hbf* __restrict__ aob) {
    int t = threadIdx.x;
    int row = blockIdx.x*8 + (t >> 5);
    int d8 = (t & 31) << 3;
    int h = d8 >> 6;
    float L = 0.0f;
    #pragma unroll
    for (int c = 0; c < 4; c++) L += lsum[(size_t)(c*4 + h)*NL + row];
    float inv = 1.0f / L;
    float s[8] = {};
    #pragma unroll
    for (int c = 0; c < 4; c++) {
        bf16x8 v = *(const bf16x8*)&op.p[c][(size_t)row*HH + d8];
        #pragma unroll
        for (int j = 0; j < 8; j++) {
            short tv = v[j]; hbf hv; *(short*)&hv = tv;
            s[j] += __bfloat162float(hv);
        }
    }
    hbf out[8];
    #pragma unroll
    for (int j = 0; j < 8; j++) out[j] = __float2bfloat16(s[j] * inv);
    *(uint4*)&aob[(size_t)row*HH + d8] = *(uint4*)out;
}

// ---------------- layernorm + pool partials: wave-per-row, barrier- and atomic-free ----------------
__global__ __launch_bounds__(256) void ln_k(const float* __restrict__ X,
                    const float* __restrict__ g, const float* __restrict__ b,
                    float* __restrict__ part) {
    int t = threadIdx.x;
    int w = t >> 6, lane = t & 63;
    int r = blockIdx.x*4 + w;
    int c4 = lane << 2;
    float4 v = *(const float4*)&X[(size_t)r*HH + c4];
    float s = v.x + v.y + v.z + v.w;
    #pragma unroll
    for (int o = 1; o < 64; o <<= 1) s += __shfl_xor(s, o);
    float mean = s * (1.0f/256.0f);
    float d0 = v.x - mean, d1 = v.y - mean, d2 = v.z - mean, d3 = v.w - mean;
    float q = d0*d0 + d1*d1 + d2*d2 + d3*d3;
    #pragma unroll
    for (int o = 1; o < 64; o <<= 1) q += __shfl_xor(q, o);
    float rstd = rsqrtf(q * (1.0f/256.0f) + 1e-5f);
    float4 gv = *(const float4*)&g[c4];
    float4 bv = *(const float4*)&b[c4];
    float4 out;
    out.x = (d0 * rstd * gv.x + bv.x) * (1.0f/512.0f);
    out.y = (d1 * rstd * gv.y + bv.y) * (1.0f/512.0f);
    out.z = (d2 * rstd * gv.z + bv.z) * (1.0f/512.0f);
    out.w = (d3 * rstd * gv.w + bv.w) * (1.0f/512.0f);
    *(float4*)&part[(size_t)(r & 511)*2048 + (r >> 9)*HH + c4] = out;
}

// reduce: 64 blocks, coalesced 32-consecutive-element reads, LDS fold of 8 slot-groups.
__global__ __launch_bounds__(256) void reduce_k(const float* __restrict__ part,
                                                float* __restrict__ pooled) {
    __shared__ float red[8][33];
    int b = blockIdx.x, t = threadIdx.x;
    int e = b*32 + (t & 31);
    int pg = t >> 5;                       // 0..7, slots pg*64 .. pg*64+63
    float s = 0.0f;
    #pragma unroll 16
    for (int p = 0; p < 64; p++)
        s += part[(size_t)(pg*64 + p)*2048 + e];
    red[pg][t & 31] = s;
    __syncthreads();
    if (t < 32) {
        float r = 0.0f;
        #pragma unroll
        for (int j = 0; j < 8; j++) r += red[j][t];
        pooled[b*32 + t] = r;
    }
}

// ---------------- heads: wave per output, bf16 transposed weights, 4 elems/lane ----------------
__global__ __launch_bounds__(256) void heads_k(const float* __restrict__ pooled,
        const hbf* __restrict__ hwt,
        const float* cbh, const float* hb, const float* tb, const float* p1b,
        const float* p2b, const float* db, const float* sb, float* __restrict__ out)
{
    int idx = blockIdx.x*4 + (threadIdx.x >> 6);
    int lane = threadIdx.x & 63;
    if (idx >= NOUT) return;
    int b = idx / 1552, j = idx - b*1552;
    const float* bi; int col;
    if (j < 1)         { bi = cbh; col = j;        }
    else if (j < 5)    { bi = hb;  col = j - 1;    }
    else if (j < 8)    { bi = tb;  col = j - 5;    }
    else if (j < 520)  { bi = p1b; col = j - 8;    }
    else if (j < 1032) { bi = p2b; col = j - 520;  }
    else if (j < 1544) { bi = db;  col = j - 1032; }
    else               { bi = sb;  col = j - 1544; }
    const float* pl = pooled + b*HH;
    const hbf* wr = hwt + (size_t)j*256;
    int k4 = lane * 4;
    float4 pv = *(const float4*)&pl[k4];
    short4 wv = *(const short4*)&wr[k4];
    hbf w0, w1, w2, w3;
    *(short*)&w0 = wv.x; *(short*)&w1 = wv.y; *(short*)&w2 = wv.z; *(short*)&w3 = wv.w;
    float s = pv.x*__bfloat162float(w0) + pv.y*__bfloat162float(w1)
            + pv.z*__bfloat162float(w2) + pv.w*__bfloat162float(w3);
    #pragma unroll
    for (int o = 32; o > 0; o >>= 1) s += __shfl_down(s, o);
    if (lane == 0) out[idx] = s + bi[col];
}

// ---------------- launcher ----------------
extern "C" void kernel_launch(void* const* d_in, const int* in_sizes, int n_in,
                              void* d_out, int out_size, void* d_ws, size_t ws_size,
                              hipStream_t stream)
{
    (void)in_sizes; (void)n_in; (void)out_size; (void)ws_size;
    const float* x      = (const float*)d_in[0];
    const int*   ei     = (const int*)  d_in[1];
    const float* W_init = (const float*)d_in[2];
    const float* b_init = (const float*)d_in[3];
    const float* g1W = (const float*)d_in[4];
    const float* g1b = (const float*)d_in[5];
    const float* g2W = (const float*)d_in[6];
    const float* g2b = (const float*)d_in[7];
    const float* inW = (const float*)d_in[8];
    const float* cW  = (const float*)d_in[9];
    const float* cb  = (const float*)d_in[10];
    const float* xpW = (const float*)d_in[11];
    const float* dtW = (const float*)d_in[12];
    const float* dtb = (const float*)d_in[13];
    const float* Alog= (const float*)d_in[14];
    const float* Dp  = (const float*)d_in[15];
    const float* outW= (const float*)d_in[16];
    const float* Wq  = (const float*)d_in[17];
    const float* bq  = (const float*)d_in[18];
    const float* Wk  = (const float*)d_in[19];
    const float* bk  = (const float*)d_in[20];
    const float* Wv  = (const float*)d_in[21];
    const float* bv  = (const float*)d_in[22];
    const float* Wo  = (const float*)d_in[23];
    const float* bo  = (const float*)d_in[24];
    const float* fusW= (const float*)d_in[25];
    const float* fusb= (const float*)d_in[26];
    const float* lng = (const float*)d_in[27];
    const float* lnb = (const float*)d_in[28];
    const float* cwp = (const float*)d_in[29];
    const float* cbp = (const float*)d_in[30];
    const float* hwp = (const float*)d_in[31];
    const float* hbp = (const float*)d_in[32];
    const float* twp = (const float*)d_in[33];
    const float* tbp = (const float*)d_in[34];
    const float* p1w = (const float*)d_in[35];
    const float* p1b = (const float*)d_in[36];
    const float* p2w = (const float*)d_in[37];
    const float* p2b = (const float*)d_in[38];
    const float* dwp = (const float*)d_in[39];
    const float* dbp = (const float*)d_in[40];
    const float* swp = (const float*)d_in[41];
    const float* sbp = (const float*)d_in[42];

    float* fw = (float*)d_ws;
    int* iw = (int*)(fw + O_INT);
    int* cnt = iw;                      // 4096 in-degree counters (zeroed by prep)
    int* csr = (int*)(fw + O_XC);       // 4096*64 bucket CSR; region reused by `fused` later

    hbf* wt   = (hbf*)(fw + O_WT);
    hbf* xb   = (hbf*)(fw + O_XB);
    hbf* h0b  = (hbf*)(fw + O_H0B);   // h0b, then h1b (reuse)
    hbf* h2b  = (hbf*)(fw + O_H2B);
    hbf* xcb  = (hbf*)(fw + O_XCB);
    hbf* dtab = (hbf*)(fw + O_DTAB);
    hbf* xzb  = (hbf*)(fw + O_XZB);
    hbf* yb   = (hbf*)(fw + O_Y);
    hbf* aob  = (hbf*)(fw + O_Y);
    hbf* catb = (hbf*)(fw + O_CATB);
    hbf* qkB  = (hbf*)(fw + O_QKB);
    hbf* vtB  = (hbf*)(fw + O_VTB);
    hbf* aggb = (hbf*)(fw + O_MBUF);  // gcn aggregation scratch (bf16)
    float* fused = fw + O_XC;         // live only after gathers are done
    float* b768 = fw + O_B768;
    float* part = fw + O_PART;
    hbf* hwt  = (hbf*)(fw + O_HWT);

    float* scanP  = fw + O_MBUF;
    float* scanHl = fw + O_QK;
    float* scanHst= fw + O_HST;
    float* lsum   = fw + O_HST;          // Hst dead after scan3

    OPtrs op;
    op.p[0] = (hbf*)(fw + O_MBUF);
    op.p[1] = (hbf*)(fw + O_MBUF + 524288);
    op.p[2] = (hbf*)(fw + O_DELTA);
    op.p[3] = (hbf*)(fw + O_DELTA + 524288);

    hbf* WtInit  = wt + 0;
    hbf* WtG1    = wt + 8192;
    hbf* WtG2    = wt + 73728;
    hbf* WtXp    = wt + 139264;
    hbf* WtDt    = wt + 155648;
    hbf* WtOut   = wt + 172032;
    hbf* WtInQKV = wt + 303104;
    hbf* WtO     = wt + 761856;
    hbf* WtFus   = wt + 827392;

    WSrc wsrc;
    wsrc.p[0]=W_init; wsrc.p[1]=g1W; wsrc.p[2]=g2W; wsrc.p[3]=xpW; wsrc.p[4]=dtW;
    wsrc.p[5]=outW; wsrc.p[6]=inW; wsrc.p[7]=Wq; wsrc.p[8]=Wk; wsrc.p[9]=Wv;
    wsrc.p[10]=Wo; wsrc.p[11]=fusW; wsrc.p[12]=p1w; wsrc.p[13]=p2w; wsrc.p[14]=dwp;
    HSrc4 hsrc;
    hsrc.p[0]=cwp; hsrc.p[1]=hwp; hsrc.p[2]=twp; hsrc.p[3]=swp;
    prep_k<<<PREP_BLKS,256,0,stream>>>(wsrc, wt, hwt, x, xb, bq, bk, bv, b768,
                                       part, cnt, hsrc);

    // graph prep: single bucket-CSR kernel
    bucket_k<<<256,256,0,stream>>>(ei, cnt, csr);

    // h0 = relu(x @ W_init + b_init) -> bf16
    mg_k<1,1><<<dim3(128,8),256,0,stream>>>((const unsigned short*)xb, (const unsigned short*)WtInit,
        b_init, h0b, 256, nullptr, nullptr, nullptr, 0, NL, 32, 256);
    // gcn1 reassociated: agg = A_hat h0 (bf16), then h1 = relu(agg @ W1 + b1)
    gather_k<<<512,256,0,stream>>>(h0b, csr, cnt, aggb);
    mg_k<1,1><<<dim3(128,8),256,0,stream>>>((const unsigned short*)aggb, (const unsigned short*)WtG1,
        g1b, h0b, 256, nullptr, nullptr, nullptr, 0, NL, 256, 256);
    // gcn2: agg = A_hat h1, then h2 = relu(agg @ W2 + b2) -> fp32 h2 + bf16 h2b + catb[0:256]
    gather_k<<<512,256,0,stream>>>(h0b, csr, cnt, aggb);
    mg_k<1,6><<<dim3(128,8),256,0,stream>>>((const unsigned short*)aggb, (const unsigned short*)WtG2,
        g2b, fw+O_H2, 256, h2b, catb, nullptr, 0, NL, 256, 256);

    // fused in_proj + QKV (N=1792): xzb | qkB (Q scaled) | vtB (transposed)
    mg_k<0,5><<<dim3(128,56),256,0,stream>>>((const unsigned short*)h2b, (const unsigned short*)WtInQKV,
        b768, xzb, 1024, qkB, vtB, nullptr, 0, NL, 256, 1792);

    // mamba
    conv_k<<<1024,256,0,stream>>>(xzb, cW, cb, xcb);
    mgp_k<<<256,256,0,stream>>>((const unsigned short*)xcb, (const unsigned short*)WtXp,
        fw+O_PROJ, dtab);
    mg_k<2,0><<<dim3(128,16),256,0,stream>>>((const unsigned short*)dtab, (const unsigned short*)WtDt,
        dtb, fw+O_DELTA, 512, nullptr, nullptr, nullptr, 0, NL, 32, 512);
    scan1_k<<<512,256,0,stream>>>(fw+O_DELTA, xcb, fw+O_PROJ, Alog, scanP, scanHl);
    scan2t_k<<<256,256,0,stream>>>(scanP, scanHl, scanHst);
    scan3_k<<<512,256,0,stream>>>(fw+O_DELTA, xcb, fw+O_PROJ, Alog, scanHst, Dp, xzb, yb);
    mg_k<0,1><<<dim3(128,8),256,0,stream>>>((const unsigned short*)yb, (const unsigned short*)WtOut,
        nullptr, catb + 256, 768, nullptr, nullptr, nullptr, 0, NL, 512, 256);

    // attention (split-K 4)
    attn_part_k<<<dim3(32,4,4),512,0,stream>>>((const unsigned short*)qkB,
        (const unsigned short*)vtB, op, lsum);
    amerge_k<<<512,256,0,stream>>>(op, lsum, aob);
    mg_k<0,1><<<dim3(128,8),256,0,stream>>>((const unsigned short*)aob, (const unsigned short*)WtO,
        bo, catb + 512, 768, nullptr, nullptr, nullptr, 0, NL, 256, 256);

    // fuse + residual + LN(+pool partials) + reduce + heads
    mg_k<1,0><<<dim3(128,8),256,0,stream>>>((const unsigned short*)catb, (const unsigned short*)WtFus,
        fusb, fused, 256, nullptr, nullptr, fw+O_H2, 256, NL, 768, 256);
    ln_k<<<1024,256,0,stream>>>(fused, lng, lnb, part);
    reduce_k<<<64,256,0,stream>>>(part, fw+O_POOL);
    heads_k<<<(NOUT+3)/4,256,0,stream>>>(fw+O_POOL, hwt, cbp,hbp,tbp,p1b,p2b,dbp,sbp,
                                         (float*)d_out);
}